// Round 17
// baseline (118.236 us; speedup 1.0000x reference)
//
#include <hip/hip_runtime.h>
#include <stdint.h>

// SINGLE-heavy-pass pipeline (R17 = R16 + fold-before-tag: pair-max FIRST,
// tag identifies the 32-key PAIR; k_finalize enumerates both keys of each
// candidate pair and lets the exact fp32 refine discard the wrong one):
//   k_norm_keys : normalize keys -> bf16 kn + invk; cast q -> qbf
//   k_pass1     : bf16 MFMA sims; per 16-result-pair merge =
//                 fm=max(fa,fb); tf=and_or(fm,mask,tagP);
//                 sec'=med3(tf,sec,hi); hi'=max(hi,tf)   (4 VALU / 2 results)
//   k_finalize  : T = 8th stream-hi - margin; emit BOTH keys of each hi/sec
//                 pair >= T into LDS cand buffer (CMAX 96, 3-chunk refine);
//                 exact fp32 re-dot -> top-8, softmax, gather, conf.
// ws: [kn N*256B][invk N*4][qbf Q*256B][shi PPART*Q*16*4][ssec same]

typedef unsigned int u32;
typedef unsigned long long u64;
typedef unsigned short u16;
typedef __attribute__((ext_vector_type(4))) float f32x4;
typedef __attribute__((ext_vector_type(2))) float f32x2;
typedef __attribute__((ext_vector_type(4))) int i32x4;
typedef __attribute__((ext_vector_type(8))) short s16x8;  // 8 bf16 in 4 VGPRs

#define D 128
#define KTILE 64     // keys per LDS tile (16 KB, single buffer) — R7-proven
#define QW 64        // queries per wave
#define QB 256       // queries per block (4 waves)
#define CMAX 96      // candidate buffer per query (pairs emit 2 keys each)
#define MARGIN 0.05f // safety margin (covers tag perturbation; vestigial)
#define TBYTES (KTILE * 256)

__device__ __forceinline__ u16 f2bf(float f) {           // RNE float->bf16
    u32 b = __float_as_uint(f);
    b += 0x7FFFu + ((b >> 16) & 1u);
    return (u16)(b >> 16);
}
__device__ __forceinline__ u32 ford(float f) {            // order-preserving f32->u32
    u32 b = __float_as_uint(f);
    return (b & 0x80000000u) ? ~b : (b | 0x80000000u);
}
__device__ __forceinline__ float ford_inv(u32 ob) {
    u32 b = (ob & 0x80000000u) ? (ob ^ 0x80000000u) : ~ob;
    return __uint_as_float(b);
}

// ------- kernel 1: normalize keys -> bf16 + invk; raw-cast q -> qbf ---------
__global__ __launch_bounds__(256) void k_norm_keys(
        const float* __restrict__ keys, const float* __restrict__ q,
        u16* __restrict__ kn, float* __restrict__ invk, u16* __restrict__ qbf,
        int N, int Q) {
    int row = blockIdx.x * 4 + (threadIdx.x >> 6);
    int lane = threadIdx.x & 63;
    if (row >= N) return;
    if (row < Q) {
        f32x2 qv = *(const f32x2*)(q + (size_t)row * D + lane * 2);
        u32 qp = (u32)f2bf(qv.x) | ((u32)f2bf(qv.y) << 16);   // RAW cast (scale-free)
        *(u32*)(qbf + (size_t)row * D + lane * 2) = qp;
    }
    const float* kr = keys + (size_t)row * D;
    f32x2 v = *(const f32x2*)(kr + lane * 2);
    float ss = v.x * v.x + v.y * v.y;
    #pragma unroll
    for (int o = 1; o < 64; o <<= 1) ss += __shfl_xor(ss, o);
    float inv = 1.0f / fmaxf(sqrtf(ss), 1e-12f);
    if (lane == 0) invk[row] = inv;
    u32 packed = (u32)f2bf(v.x * inv) | ((u32)f2bf(v.y * inv) << 16);
    *(u32*)(kn + (size_t)row * D + lane * 2) = packed;
}

// A fragments straight from qbf.
__device__ __forceinline__ void load_afr_bf(const u16* qbf, int qrow_base,
                                            int lrow, int lhi, s16x8 afr[4]) {
    const u16* qrow = qbf + (size_t)(qrow_base + lrow) * D + lhi * 8;
    #pragma unroll
    for (int s = 0; s < 4; ++s) afr[s] = *(const s16x8*)(qrow + s * 32);
}

// Block id -> (p, qb): group the nqb query-blocks of one key partition on one
// XCD (consecutive bids round-robin XCDs). Bijective when PPART % 8 == 0.
__device__ __forceinline__ void decode_bid(int bid, int nqb, int PPART,
                                           int& p, int& qb) {
    if ((PPART & 7) == 0) {
        int xcd = bid & 7, seq = bid >> 3;
        qb = seq % nqb;
        p  = (seq / nqb) * 8 + xcd;
    } else {
        p = bid / nqb; qb = bid % nqb;
    }
}

// LDS swizzle contract (R7-proven): slot (row r, 16B-granule g) holds global
// granule g ^ (r&15). Writes: reg-staged ds_write_b128 at granule g^(r&15).
// Reads: slot granule (4s+lhi)^lrow at row kt*16+lrow -> global chunk 4s+lhi.

// ---------------- kernel 2: the ONLY heavy pass — tagged top-2 per stream ---
__global__ __launch_bounds__(256, 2) void k_pass1(
        const u16* __restrict__ kn, const u16* __restrict__ qbf,
        float* __restrict__ shi, float* __restrict__ ssec,
        int Q, int N, int PPART) {
    __shared__ __align__(16) char lds[TBYTES];   // 16 KB single buffer
    const int tid = threadIdx.x;
    const int wave = tid >> 6, lane = tid & 63;
    const int lrow = lane & 15, lhi = lane >> 4;
    const int nqb = Q / QB;
    int p, qb;
    decode_bid(blockIdx.x, nqb, PPART, p, qb);
    const int part = N / PPART;
    const int key0 = p * part;
    const int qbase = qb * QB + wave * QW;

    s16x8 afr[4][4];
    #pragma unroll
    for (int qs = 0; qs < 4; ++qs) load_afr_bf(qbf, qbase + qs * 16, lrow, lhi, afr[qs]);

    float hi[4][4], sec[4][4];   // per-stream top-2 tagged pair-maxes (hi >= sec)
    #pragma unroll
    for (int qs = 0; qs < 4; ++qs)
        #pragma unroll
        for (int r = 0; r < 4; ++r) { hi[qs][r] = -3.0e38f; sec[qs][r] = -3.0e38f; }

    int roff[4];
    #pragma unroll
    for (int s = 0; s < 4; ++s)
        roff[s] = lrow * 256 + ((((s << 2) + lhi) ^ lrow) << 4);

    // staging: thread t -> row t>>2, granules (t&3)*4 + 0..3 (64B contiguous)
    const int srow = tid >> 2;
    const int sg0  = (tid & 3) << 2;
    const int sx   = srow & 15;
    int woff[4];
    #pragma unroll
    for (int i = 0; i < 4; ++i) woff[i] = srow * 256 + (((sg0 + i) ^ sx) << 4);
    const char* gsrc = (const char*)kn + ((size_t)(key0 + srow)) * 256 + sg0 * 16;

    const int iters = part / KTILE;
    i32x4 v[4];
    #pragma unroll
    for (int i = 0; i < 4; ++i) v[i] = *(const i32x4*)(gsrc + i * 16);
    const char* gnext = gsrc + TBYTES;

    const f32x4 kZero = {0.f, 0.f, 0.f, 0.f};   // hoisted acc seed

    for (int kb = 0; kb < iters; ++kb) {
        __syncthreads();   // (A) prev-tile readers done
        #pragma unroll
        for (int i = 0; i < 4; ++i) *(i32x4*)(lds + woff[i]) = v[i];
        __syncthreads();   // (B) writes visible
        if (kb + 1 < iters) {   // issue AFTER barrier; drained at next (A)
            #pragma unroll
            for (int i = 0; i < 4; ++i) v[i] = *(const i32x4*)(gnext + i * 16);
            gnext += TBYTES;
        }
        __builtin_amdgcn_s_setprio(1);
        #pragma unroll
        for (int ktp = 0; ktp < 2; ++ktp) {      // pair of 16-key tiles = 32 keys
            const u32 tagP = (u32)((kb << 1) + ktp);   // PAIR index, < 32
            s16x8 bfrA[4], bfrB[4];
            #pragma unroll
            for (int s = 0; s < 4; ++s) {
                bfrA[s] = *(const s16x8*)(lds + roff[s] + (ktp << 1) * 4096);
                bfrB[s] = *(const s16x8*)(lds + roff[s] + ((ktp << 1) + 1) * 4096);
            }
            #pragma unroll
            for (int qs = 0; qs < 4; ++qs) {
                f32x4 accA = __builtin_amdgcn_mfma_f32_16x16x32_bf16(
                                 afr[qs][0], bfrA[0], kZero, 0, 0, 0);
                f32x4 accB = __builtin_amdgcn_mfma_f32_16x16x32_bf16(
                                 afr[qs][0], bfrB[0], kZero, 0, 0, 0);
                #pragma unroll
                for (int s = 1; s < 4; ++s) {
                    accA = __builtin_amdgcn_mfma_f32_16x16x32_bf16(afr[qs][s], bfrA[s], accA, 0, 0, 0);
                    accB = __builtin_amdgcn_mfma_f32_16x16x32_bf16(afr[qs][s], bfrB[s], accB, 0, 0, 0);
                }
                #pragma unroll
                for (int r = 0; r < 4; ++r) {
                    // fold pair FIRST, then tag (pair tag -> both keys recovered later)
                    float fm = fmaxf(accA[r], accB[r]);
                    float tf = __uint_as_float(
                        (__float_as_uint(fm) & 0xFFFFFF00u) | tagP);  // v_and_or_b32
                    float h0 = hi[qs][r];
                    sec[qs][r] = __builtin_amdgcn_fmed3f(tf, sec[qs][r], h0);
                    hi[qs][r]  = fmaxf(h0, tf);
                }
            }
        }
        __builtin_amdgcn_s_setprio(0);
    }
    // layout [p][q][16]: block writes contiguous runs
    #pragma unroll
    for (int qs = 0; qs < 4; ++qs)
        #pragma unroll
        for (int r = 0; r < 4; ++r) {
            int qq = qbase + qs * 16 + (lhi << 2) + r;
            shi [((size_t)p * Q + qq) * 16 + lrow] = hi[qs][r];
            ssec[((size_t)p * Q + qq) * 16 + lrow] = sec[qs][r];
        }
}

// -------- kernel 3: FUSED threshold + collect + exact refine + output -------
__global__ __launch_bounds__(256) void k_finalize(
        const float* __restrict__ q, const float* __restrict__ keys,
        const float* __restrict__ vals, const float* __restrict__ invk,
        const float* __restrict__ shi, const float* __restrict__ ssec,
        float* __restrict__ pred, float* __restrict__ conf,
        int Q, int N, int PPART) {
    const int w = threadIdx.x >> 6;
    const int qq = blockIdx.x * 4 + w;
    const int lane = threadIdx.x & 63;
    __shared__ float qs[4][D];
    __shared__ u32 cand[4][CMAX];
    __shared__ u32 ccnt[4];
    if (lane == 0) ccnt[w] = 0u;

    // q row into LDS + exact 1/|q|
    const float* qrow = q + (size_t)qq * D;
    f32x2 qv = *(const f32x2*)(qrow + lane * 2);
    qs[w][lane * 2] = qv.x; qs[w][lane * 2 + 1] = qv.y;
    float ss = qv.x * qv.x + qv.y * qv.y;
    #pragma unroll
    for (int o = 1; o < 64; o <<= 1) ss += __shfl_xor(ss, o);
    const float invq = 1.0f / fmaxf(sqrtf(ss), 1e-12f);

    // load this query's stream top-2 (16 streams per lane for PPART=64)
    const int nv = PPART >> 2;
    float v[16], hv[16], sc[16];
    #pragma unroll
    for (int i = 0; i < 16; ++i) {
        if (i < nv) {
            size_t base = ((size_t)(i * 4 + (lane >> 4)) * Q + qq) * 16 + (lane & 15);
            hv[i] = v[i] = shi[base];
            sc[i] = ssec[base];
        } else { hv[i] = v[i] = sc[i] = -3.0e38f; }
    }
    // T = 8th-largest stream-hi (knockout; dups collapse -> smaller T = safe)
    float h = -3.0e38f;
    #pragma unroll
    for (int round = 0; round < 8; ++round) {
        h = v[0];
        #pragma unroll
        for (int i = 1; i < 16; ++i) h = fmaxf(h, v[i]);
        #pragma unroll
        for (int o = 1; o < 64; o <<= 1) h = fmaxf(h, __shfl_xor(h, o));
        #pragma unroll
        for (int i = 0; i < 16; ++i) if (v[i] == h) v[i] = -3.0e38f;
    }
    const float T = h - MARGIN;
    const int part = N / PPART;
    #pragma unroll
    for (int i = 0; i < 16; ++i) {
        if (i >= nv) break;
        const int sidx = i * 64 + lane;        // stream = (p = sidx>>4, j = sidx&15)
        const int p = sidx >> 4, j = sidx & 15;
        if (hv[i] >= T) {                      // pair entry -> emit BOTH keys
            u32 k0 = (u32)(p * part + (int)((__float_as_uint(hv[i]) & 255u) << 5) + j);
            u32 pos = atomicAdd(&ccnt[w], 2u);
            if (pos < CMAX) cand[w][pos] = k0;
            if (pos + 1 < CMAX) cand[w][pos + 1] = k0 + 16u;
        }
        if (sc[i] >= T) {
            u32 k0 = (u32)(p * part + (int)((__float_as_uint(sc[i]) & 255u) << 5) + j);
            u32 pos = atomicAdd(&ccnt[w], 2u);
            if (pos < CMAX) cand[w][pos] = k0;
            if (pos + 1 < CMAX) cand[w][pos + 1] = k0 + 16u;
        }
    }
    __syncthreads();   // qs + cand + ccnt visible to all lanes

    const u32 n = min(ccnt[w], (u32)CMAX);   // >= 8 by construction
    const int c0 = lane >> 1;                // candidates c0, c0+32, c0+64
    const int half = lane & 1;
    const bool valid0 = (u32)c0 < n;
    const bool valid1 = (u32)(c0 + 32) < n;
    const bool valid2 = (u32)(c0 + 64) < n;
    const u32 key0 = valid0 ? cand[w][c0] : 0u;
    const u32 key1 = valid1 ? cand[w][c0 + 32] : 0u;
    const u32 key2 = valid2 ? cand[w][c0 + 64] : 0u;

    const float* qsp = &qs[w][half * 64];
    float dot0 = 0.f, dot1 = 0.f, dot2 = 0.f;
    {
        const float* kr0 = keys + (size_t)key0 * D + half * 64;
        const float* kr1 = keys + (size_t)key1 * D + half * 64;
        const float* kr2 = keys + (size_t)key2 * D + half * 64;
        #pragma unroll
        for (int j = 0; j < 64; j += 4) {
            f32x4 a = *(const f32x4*)(kr0 + j);
            f32x4 b = *(const f32x4*)(kr1 + j);
            f32x4 c = *(const f32x4*)(kr2 + j);
            dot0 += a.x * qsp[j] + a.y * qsp[j + 1] + a.z * qsp[j + 2] + a.w * qsp[j + 3];
            dot1 += b.x * qsp[j] + b.y * qsp[j + 1] + b.z * qsp[j + 2] + b.w * qsp[j + 3];
            dot2 += c.x * qsp[j] + c.y * qsp[j + 1] + c.z * qsp[j + 2] + c.w * qsp[j + 3];
        }
    }
    dot0 += __shfl_xor(dot0, 1);
    dot1 += __shfl_xor(dot1, 1);
    dot2 += __shfl_xor(dot2, 1);
    const float ex0 = dot0 * invk[key0] * invq;
    const float ex1 = dot1 * invk[key1] * invq;
    const float ex2 = dot2 * invk[key2] * invq;
    // pack with ~key so ties prefer the smaller index (jax top_k order)
    u64 pkA = valid0 ? (((u64)ford(ex0) << 32) | (u32)(~key0)) : 0ull;
    u64 pkB = valid1 ? (((u64)ford(ex1) << 32) | (u32)(~key1)) : 0ull;
    u64 pkC = valid2 ? (((u64)ford(ex2) << 32) | (u32)(~key2)) : 0ull;

    float accA = 0.f, accB = 0.f, wsum = 0.f, vsum = 0.f, vmax = 0.f;
    #pragma unroll
    for (int r = 0; r < 8; ++r) {
        u64 mx = pkA > pkB ? pkA : pkB;
        mx = pkC > mx ? pkC : mx;
        u64 hh = mx;
        #pragma unroll
        for (int o = 1; o < 64; o <<= 1) {
            u64 tt = __shfl_xor(hh, o);
            hh = tt > hh ? tt : hh;
        }
        const bool ok = (hh != 0ull);
        const float vv = ford_inv((u32)(hh >> 32));
        const u32 idx = ok ? ~((u32)hh) : 0u;
        if (r == 0) vmax = vv;
        const float wgt = ok ? expf(vv - vmax) : 0.f;
        wsum += wgt; vsum += ok ? vv : 0.f;
        const float* vr = vals + (size_t)idx * D;
        accA += wgt * vr[lane];
        accB += wgt * vr[lane + 64];
        if (pkA == hh) pkA = 0ull;   // pop winner (keys unique -> pk unique)
        if (pkB == hh) pkB = 0ull;
        if (pkC == hh) pkC = 0ull;
    }
    const float inv_ws = 1.0f / wsum;
    pred[(size_t)qq * D + lane] = accA * inv_ws;
    pred[(size_t)qq * D + lane + 64] = accB * inv_ws;
    if (lane == 0) conf[qq] = fminf(fmaxf(vsum * 0.125f, 0.f), 1.f);
}

// ---------------------------------------------------------------------------
extern "C" void kernel_launch(void* const* d_in, const int* in_sizes, int n_in,
                              void* d_out, int out_size, void* d_ws, size_t ws_size,
                              hipStream_t stream) {
    const float* q    = (const float*)d_in[0];
    const float* keys = (const float*)d_in[1];
    const float* vals = (const float*)d_in[2];
    const int Q = in_sizes[0] / D;
    const int N = in_sizes[1] / D;

    int PPART = 64;  // 1024 blocks; floor 16 keeps the 8-bit pair tag in range
    auto need = [&](int P) {
        return (size_t)N * D * 2 + (size_t)N * 4 + (size_t)Q * D * 2 +
               2 * ((size_t)Q * P * 16 * 4);
    };
    while (PPART > 16 && need(PPART) > ws_size) PPART >>= 1;

    char* ws = (char*)d_ws;
    size_t off = 0;
    u16*   kn   = (u16*)(ws + off);   off += (size_t)N * D * 2;
    float* invk = (float*)(ws + off); off += (size_t)N * 4;
    u16*   qbf  = (u16*)(ws + off);   off += (size_t)Q * D * 2;
    float* shi  = (float*)(ws + off); off += (size_t)Q * PPART * 16 * 4;
    float* ssec = (float*)(ws + off); off += (size_t)Q * PPART * 16 * 4;

    float* pred = (float*)d_out;
    float* conf = pred + (size_t)Q * D;

    k_norm_keys<<<(N + 3) / 4, 256, 0, stream>>>(keys, q, kn, invk, qbf, N, Q);
    k_pass1<<<(Q / QB) * PPART, 256, 0, stream>>>(kn, qbf, shi, ssec, Q, N, PPART);
    k_finalize<<<Q / 4, 256, 0, stream>>>(q, keys, vals, invk, shi, ssec,
                                          pred, conf, Q, N, PPART);
}

// Round 18
// 106.323 us; speedup vs baseline: 1.1120x; 1.1120x over previous
//
#include <hip/hip_runtime.h>
#include <stdint.h>

// SINGLE-heavy-pass pipeline (R18 = byte-exact revert to R16, the proven best
// at 105.7 us. R17's fold-before-tag regressed: the pair-max join serialized
// the two MFMA dependency chains before any merge op — latency, not op-count,
// governs at ~2 waves/SIMD):
//   k_norm_keys : normalize keys -> bf16 kn + invk; cast q -> qbf
//   k_pass1     : bf16 MFMA sims, 8-bit tile tag in low mantissa bits
//                 (err <= 3e-5 << MARGIN); per-stream branchless top-2,
//                 PAIR-merged: hi'=max3(hi,fa,fb); sec'=max(med3(hi,fa,fb),sec)
//   k_finalize  : FUSED select+final: T = 8th stream-hi - margin; collect
//                 hi/sec >= T into LDS cand buffer; exact fp32 re-dot ->
//                 top-8, softmax, gather, conf.
// ws: [kn N*256B][invk N*4][qbf Q*256B][shi PPART*Q*16*4][ssec same]

typedef unsigned int u32;
typedef unsigned long long u64;
typedef unsigned short u16;
typedef __attribute__((ext_vector_type(4))) float f32x4;
typedef __attribute__((ext_vector_type(2))) float f32x2;
typedef __attribute__((ext_vector_type(4))) int i32x4;
typedef __attribute__((ext_vector_type(8))) short s16x8;  // 8 bf16 in 4 VGPRs

#define D 128
#define KTILE 64     // keys per LDS tile (16 KB, single buffer) — R7-proven
#define QW 64        // queries per wave
#define QB 256       // queries per block (4 waves)
#define CMAX 64      // candidate buffer per query
#define MARGIN 0.05f // threshold safety margin (covers bf16 + tag perturbation)
#define TBYTES (KTILE * 256)

__device__ __forceinline__ u16 f2bf(float f) {           // RNE float->bf16
    u32 b = __float_as_uint(f);
    b += 0x7FFFu + ((b >> 16) & 1u);
    return (u16)(b >> 16);
}
__device__ __forceinline__ u32 ford(float f) {            // order-preserving f32->u32
    u32 b = __float_as_uint(f);
    return (b & 0x80000000u) ? ~b : (b | 0x80000000u);
}
__device__ __forceinline__ float ford_inv(u32 ob) {
    u32 b = (ob & 0x80000000u) ? (ob ^ 0x80000000u) : ~ob;
    return __uint_as_float(b);
}

// ------- kernel 1: normalize keys -> bf16 + invk; raw-cast q -> qbf ---------
__global__ __launch_bounds__(256) void k_norm_keys(
        const float* __restrict__ keys, const float* __restrict__ q,
        u16* __restrict__ kn, float* __restrict__ invk, u16* __restrict__ qbf,
        int N, int Q) {
    int row = blockIdx.x * 4 + (threadIdx.x >> 6);
    int lane = threadIdx.x & 63;
    if (row >= N) return;
    if (row < Q) {
        f32x2 qv = *(const f32x2*)(q + (size_t)row * D + lane * 2);
        u32 qp = (u32)f2bf(qv.x) | ((u32)f2bf(qv.y) << 16);   // RAW cast (scale-free)
        *(u32*)(qbf + (size_t)row * D + lane * 2) = qp;
    }
    const float* kr = keys + (size_t)row * D;
    f32x2 v = *(const f32x2*)(kr + lane * 2);
    float ss = v.x * v.x + v.y * v.y;
    #pragma unroll
    for (int o = 1; o < 64; o <<= 1) ss += __shfl_xor(ss, o);
    float inv = 1.0f / fmaxf(sqrtf(ss), 1e-12f);
    if (lane == 0) invk[row] = inv;
    u32 packed = (u32)f2bf(v.x * inv) | ((u32)f2bf(v.y * inv) << 16);
    *(u32*)(kn + (size_t)row * D + lane * 2) = packed;
}

// A fragments straight from qbf.
__device__ __forceinline__ void load_afr_bf(const u16* qbf, int qrow_base,
                                            int lrow, int lhi, s16x8 afr[4]) {
    const u16* qrow = qbf + (size_t)(qrow_base + lrow) * D + lhi * 8;
    #pragma unroll
    for (int s = 0; s < 4; ++s) afr[s] = *(const s16x8*)(qrow + s * 32);
}

// Block id -> (p, qb): group the nqb query-blocks of one key partition on one
// XCD (consecutive bids round-robin XCDs). Bijective when PPART % 8 == 0.
__device__ __forceinline__ void decode_bid(int bid, int nqb, int PPART,
                                           int& p, int& qb) {
    if ((PPART & 7) == 0) {
        int xcd = bid & 7, seq = bid >> 3;
        qb = seq % nqb;
        p  = (seq / nqb) * 8 + xcd;
    } else {
        p = bid / nqb; qb = bid % nqb;
    }
}

// LDS swizzle contract (R7-proven): slot (row r, 16B-granule g) holds global
// granule g ^ (r&15). Writes: reg-staged ds_write_b128 at granule g^(r&15).
// Reads: slot granule (4s+lhi)^lrow at row kt*16+lrow -> global chunk 4s+lhi.

// ---------------- kernel 2: the ONLY heavy pass — tagged top-2 per stream ---
__global__ __launch_bounds__(256, 2) void k_pass1(
        const u16* __restrict__ kn, const u16* __restrict__ qbf,
        float* __restrict__ shi, float* __restrict__ ssec,
        int Q, int N, int PPART) {
    __shared__ __align__(16) char lds[TBYTES];   // 16 KB single buffer
    const int tid = threadIdx.x;
    const int wave = tid >> 6, lane = tid & 63;
    const int lrow = lane & 15, lhi = lane >> 4;
    const int nqb = Q / QB;
    int p, qb;
    decode_bid(blockIdx.x, nqb, PPART, p, qb);
    const int part = N / PPART;
    const int key0 = p * part;
    const int qbase = qb * QB + wave * QW;

    s16x8 afr[4][4];
    #pragma unroll
    for (int qs = 0; qs < 4; ++qs) load_afr_bf(qbf, qbase + qs * 16, lrow, lhi, afr[qs]);

    float hi[4][4], sec[4][4];   // per-stream top-2 tagged values (hi >= sec)
    #pragma unroll
    for (int qs = 0; qs < 4; ++qs)
        #pragma unroll
        for (int r = 0; r < 4; ++r) { hi[qs][r] = -3.0e38f; sec[qs][r] = -3.0e38f; }

    int roff[4];
    #pragma unroll
    for (int s = 0; s < 4; ++s)
        roff[s] = lrow * 256 + ((((s << 2) + lhi) ^ lrow) << 4);

    // staging: thread t -> row t>>2, granules (t&3)*4 + 0..3 (64B contiguous)
    const int srow = tid >> 2;
    const int sg0  = (tid & 3) << 2;
    const int sx   = srow & 15;
    int woff[4];
    #pragma unroll
    for (int i = 0; i < 4; ++i) woff[i] = srow * 256 + (((sg0 + i) ^ sx) << 4);
    const char* gsrc = (const char*)kn + ((size_t)(key0 + srow)) * 256 + sg0 * 16;

    const int iters = part / KTILE;
    i32x4 v[4];
    #pragma unroll
    for (int i = 0; i < 4; ++i) v[i] = *(const i32x4*)(gsrc + i * 16);
    const char* gnext = gsrc + TBYTES;

    const f32x4 kZero = {0.f, 0.f, 0.f, 0.f};   // hoisted acc seed

    for (int kb = 0; kb < iters; ++kb) {
        __syncthreads();   // (A) prev-tile readers done
        #pragma unroll
        for (int i = 0; i < 4; ++i) *(i32x4*)(lds + woff[i]) = v[i];
        __syncthreads();   // (B) writes visible
        if (kb + 1 < iters) {   // issue AFTER barrier; drained at next (A)
            #pragma unroll
            for (int i = 0; i < 4; ++i) v[i] = *(const i32x4*)(gnext + i * 16);
            gnext += TBYTES;
        }
        __builtin_amdgcn_s_setprio(1);
        #pragma unroll
        for (int ktp = 0; ktp < 2; ++ktp) {      // pair of 16-key tiles
            const u32 tagA = (u32)((kb << 2) + (ktp << 1));
            const u32 tagB = tagA + 1u;
            s16x8 bfrA[4], bfrB[4];
            #pragma unroll
            for (int s = 0; s < 4; ++s) {
                bfrA[s] = *(const s16x8*)(lds + roff[s] + (ktp << 1) * 4096);
                bfrB[s] = *(const s16x8*)(lds + roff[s] + ((ktp << 1) + 1) * 4096);
            }
            #pragma unroll
            for (int qs = 0; qs < 4; ++qs) {
                f32x4 accA = __builtin_amdgcn_mfma_f32_16x16x32_bf16(
                                 afr[qs][0], bfrA[0], kZero, 0, 0, 0);
                f32x4 accB = __builtin_amdgcn_mfma_f32_16x16x32_bf16(
                                 afr[qs][0], bfrB[0], kZero, 0, 0, 0);
                #pragma unroll
                for (int s = 1; s < 4; ++s) {
                    accA = __builtin_amdgcn_mfma_f32_16x16x32_bf16(afr[qs][s], bfrA[s], accA, 0, 0, 0);
                    accB = __builtin_amdgcn_mfma_f32_16x16x32_bf16(afr[qs][s], bfrB[s], accB, 0, 0, 0);
                }
                #pragma unroll
                for (int r = 0; r < 4; ++r) {
                    // tag both results (backend fuses to v_and_or_b32)
                    float fa = __uint_as_float(
                        (__float_as_uint(accA[r]) & 0xFFFFFF00u) | tagA);
                    float fb = __uint_as_float(
                        (__float_as_uint(accB[r]) & 0xFFFFFF00u) | tagB);
                    float h0 = hi[qs][r];
                    // top-2 merge of {h0, sec} U {fa, fb}  (sec <= h0)
                    sec[qs][r] = fmaxf(__builtin_amdgcn_fmed3f(h0, fa, fb), sec[qs][r]);
                    hi[qs][r]  = fmaxf(fmaxf(h0, fa), fb);   // -> v_max3_f32
                }
            }
        }
        __builtin_amdgcn_s_setprio(0);
    }
    // layout [p][q][16]: block writes contiguous runs
    #pragma unroll
    for (int qs = 0; qs < 4; ++qs)
        #pragma unroll
        for (int r = 0; r < 4; ++r) {
            int qq = qbase + qs * 16 + (lhi << 2) + r;
            shi [((size_t)p * Q + qq) * 16 + lrow] = hi[qs][r];
            ssec[((size_t)p * Q + qq) * 16 + lrow] = sec[qs][r];
        }
}

// -------- kernel 3: FUSED threshold + collect + exact refine + output -------
__global__ __launch_bounds__(256) void k_finalize(
        const float* __restrict__ q, const float* __restrict__ keys,
        const float* __restrict__ vals, const float* __restrict__ invk,
        const float* __restrict__ shi, const float* __restrict__ ssec,
        float* __restrict__ pred, float* __restrict__ conf,
        int Q, int N, int PPART) {
    const int w = threadIdx.x >> 6;
    const int qq = blockIdx.x * 4 + w;
    const int lane = threadIdx.x & 63;
    __shared__ float qs[4][D];
    __shared__ u32 cand[4][CMAX];
    __shared__ u32 ccnt[4];
    if (lane == 0) ccnt[w] = 0u;

    // q row into LDS + exact 1/|q|
    const float* qrow = q + (size_t)qq * D;
    f32x2 qv = *(const f32x2*)(qrow + lane * 2);
    qs[w][lane * 2] = qv.x; qs[w][lane * 2 + 1] = qv.y;
    float ss = qv.x * qv.x + qv.y * qv.y;
    #pragma unroll
    for (int o = 1; o < 64; o <<= 1) ss += __shfl_xor(ss, o);
    const float invq = 1.0f / fmaxf(sqrtf(ss), 1e-12f);

    // load this query's stream top-2 (16 streams per lane for PPART=64)
    const int nv = PPART >> 2;
    float v[16], hv[16], sc[16];
    #pragma unroll
    for (int i = 0; i < 16; ++i) {
        if (i < nv) {
            size_t base = ((size_t)(i * 4 + (lane >> 4)) * Q + qq) * 16 + (lane & 15);
            hv[i] = v[i] = shi[base];
            sc[i] = ssec[base];
        } else { hv[i] = v[i] = sc[i] = -3.0e38f; }
    }
    // T = 8th-largest stream-hi (knockout; dups collapse -> smaller T = safe)
    float h = -3.0e38f;
    #pragma unroll
    for (int round = 0; round < 8; ++round) {
        h = v[0];
        #pragma unroll
        for (int i = 1; i < 16; ++i) h = fmaxf(h, v[i]);
        #pragma unroll
        for (int o = 1; o < 64; o <<= 1) h = fmaxf(h, __shfl_xor(h, o));
        #pragma unroll
        for (int i = 0; i < 16; ++i) if (v[i] == h) v[i] = -3.0e38f;
    }
    const float T = h - MARGIN;
    const int part = N / PPART;
    #pragma unroll
    for (int i = 0; i < 16; ++i) {
        if (i >= nv) break;
        const int sidx = i * 64 + lane;        // stream = (p = sidx>>4, j = sidx&15)
        const int p = sidx >> 4, j = sidx & 15;
        if (hv[i] >= T) {                      // rare (~10-20 per query)
            u32 key = (u32)(p * part + (int)((__float_as_uint(hv[i]) & 255u) << 4) + j);
            u32 pos = atomicAdd(&ccnt[w], 1u);
            if (pos < CMAX) cand[w][pos] = key;
        }
        if (sc[i] >= T) {
            u32 key = (u32)(p * part + (int)((__float_as_uint(sc[i]) & 255u) << 4) + j);
            u32 pos = atomicAdd(&ccnt[w], 1u);
            if (pos < CMAX) cand[w][pos] = key;
        }
    }
    __syncthreads();   // qs + cand + ccnt visible to all lanes

    const u32 n = min(ccnt[w], (u32)CMAX);   // >= 8 by construction
    const int c0 = lane >> 1;                // candidates c0 and c0+32
    const int half = lane & 1;
    const bool valid0 = (u32)c0 < n;
    const bool valid1 = (u32)(c0 + 32) < n;
    const u32 key0 = valid0 ? cand[w][c0] : 0u;
    const u32 key1 = valid1 ? cand[w][c0 + 32] : 0u;

    const float* qsp = &qs[w][half * 64];
    float dot0 = 0.f, dot1 = 0.f;
    {
        const float* kr0 = keys + (size_t)key0 * D + half * 64;
        const float* kr1 = keys + (size_t)key1 * D + half * 64;
        #pragma unroll
        for (int j = 0; j < 64; j += 4) {
            f32x4 a = *(const f32x4*)(kr0 + j);
            f32x4 b = *(const f32x4*)(kr1 + j);
            dot0 += a.x * qsp[j] + a.y * qsp[j + 1] + a.z * qsp[j + 2] + a.w * qsp[j + 3];
            dot1 += b.x * qsp[j] + b.y * qsp[j + 1] + b.z * qsp[j + 2] + b.w * qsp[j + 3];
        }
    }
    dot0 += __shfl_xor(dot0, 1);
    dot1 += __shfl_xor(dot1, 1);
    const float ex0 = dot0 * invk[key0] * invq;
    const float ex1 = dot1 * invk[key1] * invq;
    // pack with ~key so ties prefer the smaller index (jax top_k order)
    u64 pkA = valid0 ? (((u64)ford(ex0) << 32) | (u32)(~key0)) : 0ull;
    u64 pkB = valid1 ? (((u64)ford(ex1) << 32) | (u32)(~key1)) : 0ull;

    float accA = 0.f, accB = 0.f, wsum = 0.f, vsum = 0.f, vmax = 0.f;
    #pragma unroll
    for (int r = 0; r < 8; ++r) {
        u64 mx = pkA > pkB ? pkA : pkB;
        u64 hh = mx;
        #pragma unroll
        for (int o = 1; o < 64; o <<= 1) {
            u64 tt = __shfl_xor(hh, o);
            hh = tt > hh ? tt : hh;
        }
        const bool ok = (hh != 0ull);
        const float vv = ford_inv((u32)(hh >> 32));
        const u32 idx = ok ? ~((u32)hh) : 0u;
        if (r == 0) vmax = vv;
        const float wgt = ok ? expf(vv - vmax) : 0.f;
        wsum += wgt; vsum += ok ? vv : 0.f;
        const float* vr = vals + (size_t)idx * D;
        accA += wgt * vr[lane];
        accB += wgt * vr[lane + 64];
        if (pkA == hh) pkA = 0ull;   // pop winner (keys unique -> pk unique)
        if (pkB == hh) pkB = 0ull;
    }
    const float inv_ws = 1.0f / wsum;
    pred[(size_t)qq * D + lane] = accA * inv_ws;
    pred[(size_t)qq * D + lane + 64] = accB * inv_ws;
    if (lane == 0) conf[qq] = fminf(fmaxf(vsum * 0.125f, 0.f), 1.f);
}

// ---------------------------------------------------------------------------
extern "C" void kernel_launch(void* const* d_in, const int* in_sizes, int n_in,
                              void* d_out, int out_size, void* d_ws, size_t ws_size,
                              hipStream_t stream) {
    const float* q    = (const float*)d_in[0];
    const float* keys = (const float*)d_in[1];
    const float* vals = (const float*)d_in[2];
    const int Q = in_sizes[0] / D;
    const int N = in_sizes[1] / D;

    int PPART = 64;  // 1024 blocks; floor 16 keeps the 8-bit tag in range
    auto need = [&](int P) {
        return (size_t)N * D * 2 + (size_t)N * 4 + (size_t)Q * D * 2 +
               2 * ((size_t)Q * P * 16 * 4);
    };
    while (PPART > 16 && need(PPART) > ws_size) PPART >>= 1;

    char* ws = (char*)d_ws;
    size_t off = 0;
    u16*   kn   = (u16*)(ws + off);   off += (size_t)N * D * 2;
    float* invk = (float*)(ws + off); off += (size_t)N * 4;
    u16*   qbf  = (u16*)(ws + off);   off += (size_t)Q * D * 2;
    float* shi  = (float*)(ws + off); off += (size_t)Q * PPART * 16 * 4;
    float* ssec = (float*)(ws + off); off += (size_t)Q * PPART * 16 * 4;

    float* pred = (float*)d_out;
    float* conf = pred + (size_t)Q * D;

    k_norm_keys<<<(N + 3) / 4, 256, 0, stream>>>(keys, q, kn, invk, qbf, N, Q);
    k_pass1<<<(Q / QB) * PPART, 256, 0, stream>>>(kn, qbf, shi, ssec, Q, N, PPART);
    k_finalize<<<Q / 4, 256, 0, stream>>>(q, keys, vals, invk, shi, ssec,
                                          pred, conf, Q, N, PPART);
}